// Round 2
// baseline (575.120 us; speedup 1.0000x reference)
//
#include <hip/hip_runtime.h>
#include <hip/hip_bf16.h>
#include <stdint.h>

typedef float  f32x4 __attribute__((ext_vector_type(4)));
typedef short  s16x8 __attribute__((ext_vector_type(8)));
typedef uint32_t u32x4 __attribute__((ext_vector_type(4)));

// round-to-nearest-even float -> bf16 bits (data has no NaN/Inf)
__device__ __forceinline__ uint16_t f2bf(float f) {
    union { float f; uint32_t u; } a; a.f = f;
    uint32_t r = a.u + 0x7FFFu + ((a.u >> 16) & 1u);
    return (uint16_t)(r >> 16);
}
__device__ __forceinline__ float lrelu(float v) { return fmaxf(v, 0.1f * v); }

// ---------------------------------------------------------------------------
// prep1: blocks 0..15 -> hidden (lrelu(deg@w1^T)) + CA attention for sample b.
//        block 16     -> pack conv_w into MFMA B-fragment order (bf16):
//        Wp[((ot*4+kk)*64+lane)*8+j] = conv_w[o=ot*16+(lane&15)][c=kk*32+(lane>>4)*8+j]
// ---------------------------------------------------------------------------
__global__ __launch_bounds__(128) void prep1_kernel(
    const float* __restrict__ deg, const float* __restrict__ w1,
    const float* __restrict__ conv_w, const float* __restrict__ ca_w1,
    const float* __restrict__ ca_w2,
    float* __restrict__ hid_ws, float* __restrict__ att_ws,
    uint16_t* __restrict__ Wp)
{
    const int t = threadIdx.x;
    if (blockIdx.x < 16) {
        const int b = blockIdx.x;
        __shared__ float sdeg[128];
        __shared__ float sh2[16];
        sdeg[t] = deg[b * 128 + t];
        __syncthreads();
        {
            float acc = 0.f;
            const float* w1r = w1 + t * 128;
            for (int c = 0; c < 128; ++c) acc += sdeg[c] * w1r[c];
            hid_ws[b * 128 + t] = lrelu(acc);
        }
        if (t < 16) {
            float a2 = 0.f;
            const float* cw = ca_w1 + t * 128;
            for (int c = 0; c < 128; ++c) a2 += sdeg[c] * cw[c];
            sh2[t] = lrelu(a2);
        }
        __syncthreads();
        {
            float aa = 0.f;
            const float* c2 = ca_w2 + t * 16;
            #pragma unroll
            for (int r = 0; r < 16; ++r) aa += sh2[r] * c2[r];
            att_ws[b * 128 + t] = 1.f / (1.f + expf(-aa));
        }
    } else {
        for (int idx = t; idx < 16384; idx += 128) {
            int j    = idx & 7;
            int lane = (idx >> 3) & 63;
            int kk   = (idx >> 9) & 3;
            int ot   = idx >> 11;
            int o = ot * 16 + (lane & 15);
            int c = kk * 32 + ((lane >> 4) & 3) * 8 + j;
            Wp[idx] = f2bf(conv_w[o * 128 + c]);
        }
    }
}

// ---------------------------------------------------------------------------
// prep2: kern taps. grid (16, 6) x 256 threads; thread -> one (c, tap) dot.
//        kern_ws padded [c][12] so main can float4-load taps.
// ---------------------------------------------------------------------------
__global__ __launch_bounds__(256) void prep2_kernel(
    const float* __restrict__ hid_ws, const float* __restrict__ w2,
    float* __restrict__ kern_ws)
{
    const int b  = blockIdx.x;
    const int cj = blockIdx.y * 256 + threadIdx.x;   // 0..1535
    __shared__ f32x4 shid[32];
    if (threadIdx.x < 32)
        shid[threadIdx.x] = *(const f32x4*)(hid_ws + b * 128 + threadIdx.x * 4);
    __syncthreads();
    if (cj < 1152) {
        const int c = cj / 9, j = cj - c * 9;
        const f32x4* row = (const f32x4*)(w2 + cj * 128);
        float acc = 0.f;
        #pragma unroll 8
        for (int r = 0; r < 32; ++r) {
            f32x4 a = shid[r], v = row[r];
            acc += a.x * v.x + a.y * v.y + a.z * v.z + a.w * v.w;
        }
        kern_ws[(b * 128 + c) * 12 + j] = acc;
    } else {
        const int z = cj - 1152;            // 0..383 -> zero the pad lanes
        const int c = z / 3, j = 9 + (z - (z / 3) * 3);
        kern_ws[(b * 128 + c) * 12 + j] = 0.f;
    }
}

// ---------------------------------------------------------------------------
// Main fused kernel: one block per (b, h) row; 256 threads = 4 waves.
// Phase 1: depthwise 3x3 + lrelu -> bf16 y tile in LDS (w,c layout, XOR swizzle).
// Phase 2: transposed MFMA GEMM D[w][o] = sum_c y^T[w][c] * W^T[c][o]
//          (operand-swap = free transpose; fragment addressing unchanged).
// Phase 3: stage D through LDS (padded [64][132] f32, two o-halves) ->
//          fully-linear dwordx4 stores (full 128B lines) + residual x0*att.
// ---------------------------------------------------------------------------
__global__ __launch_bounds__(256, 4) void main_kernel(
    const float* __restrict__ x0, const float* __restrict__ kern_ws,
    const float* __restrict__ att_ws, const uint16_t* __restrict__ Wp,
    const float* __restrict__ conv_b, float* __restrict__ out)
{
    __shared__ char smem[64 * 132 * 4];           // 33792 B
    uint16_t* y_s   = (uint16_t*)smem;            // phase 1/2 view (32 KiB used)
    float*    ystage = (float*)smem;              // phase 3 view [64][132]

    // XCD-aware swizzle (2048 % 8 == 0 -> bijective); adjacent h rows share halos.
    const int bid = blockIdx.x;
    const int lg  = (bid & 7) * 256 + (bid >> 3);
    const int b = lg >> 7;
    const int h = lg & 127;

    const int t    = threadIdx.x;
    const int lane = t & 63;
    const int q    = t >> 6;
    const int c0   = (t >> 4) * 8;    // channel octet (phase 1)
    const int w0   = (t & 15) * 8;    // w range (phase 1)

    // ---- kern taps for my 8 channels ----
    float kf[8][9];
    #pragma unroll
    for (int cc = 0; cc < 8; ++cc) {
        const float* kp = kern_ws + (b * 128 + c0 + cc) * 12;
        f32x4 ka = *(const f32x4*)kp;
        f32x4 kb = *(const f32x4*)(kp + 4);
        kf[cc][0] = ka.x; kf[cc][1] = ka.y; kf[cc][2] = ka.z; kf[cc][3] = ka.w;
        kf[cc][4] = kb.x; kf[cc][5] = kb.y; kf[cc][6] = kb.z; kf[cc][7] = kb.w;
        kf[cc][8] = kp[8];
    }

    // ---- depthwise 3x3 + lrelu -> packed bf16 ----
    uint32_t ypk[8][4];
    #pragma unroll
    for (int cc = 0; cc < 8; ++cc) {
        const int c = c0 + cc;
        const float* xpl = x0 + (b * 128 + c) * (128 * 128);
        float a8[8];
        #pragma unroll
        for (int i = 0; i < 8; ++i) a8[i] = 0.f;
        #pragma unroll
        for (int dr = 0; dr < 3; ++dr) {
            const int r = h - 1 + dr;
            f32x4 f0, f1;
            if ((unsigned)r < 128u) {
                const float* rp = xpl + r * 128 + w0;
                f0 = *(const f32x4*)rp;
                f1 = *(const f32x4*)(rp + 4);
            } else {
                f0.x = f0.y = f0.z = f0.w = 0.f;
                f1.x = f1.y = f1.z = f1.w = 0.f;
            }
            float lft = __shfl(f1.w, (lane - 1) & 63);
            float rgt = __shfl(f0.x, (lane + 1) & 63);
            if ((t & 15) == 0)  lft = 0.f;
            if ((t & 15) == 15) rgt = 0.f;
            const float k0 = kf[cc][dr * 3 + 0];
            const float k1 = kf[cc][dr * 3 + 1];
            const float k2 = kf[cc][dr * 3 + 2];
            a8[0] += k0 * lft  + k1 * f0.x + k2 * f0.y;
            a8[1] += k0 * f0.x + k1 * f0.y + k2 * f0.z;
            a8[2] += k0 * f0.y + k1 * f0.z + k2 * f0.w;
            a8[3] += k0 * f0.z + k1 * f0.w + k2 * f1.x;
            a8[4] += k0 * f0.w + k1 * f1.x + k2 * f1.y;
            a8[5] += k0 * f1.x + k1 * f1.y + k2 * f1.z;
            a8[6] += k0 * f1.y + k1 * f1.z + k2 * f1.w;
            a8[7] += k0 * f1.z + k1 * f1.w + k2 * rgt;
        }
        #pragma unroll
        for (int wi = 0; wi < 8; ++wi) {
            uint32_t u = f2bf(lrelu(a8[wi]));
            if ((cc & 1) == 0) ypk[wi][cc >> 1] = u;
            else               ypk[wi][cc >> 1] |= (u << 16);
        }
    }
    #pragma unroll
    for (int wi = 0; wi < 8; ++wi) {
        const int w = w0 + wi;
        int off = w * 256 + c0 * 2;
        off ^= (((w & 7) ^ ((w >> 3) & 7)) << 4);
        u32x4 v; v.x = ypk[wi][0]; v.y = ypk[wi][1]; v.z = ypk[wi][2]; v.w = ypk[wi][3];
        *(u32x4*)((char*)y_s + off) = v;
    }

    // ---- GEMM: wave q -> w-half mh, o-half oh; D[w][o] (transposed) ----
    const int mh = q >> 1;
    const int oh = q & 1;
    s16x8 Bf[4][4];                                  // W^T fragments (held)
    #pragma unroll
    for (int nt = 0; nt < 4; ++nt)
        #pragma unroll
        for (int kk = 0; kk < 4; ++kk)
            Bf[nt][kk] = *(const s16x8*)(Wp + (((oh * 4 + nt) * 4 + kk) * 64 + lane) * 8);
    float cb[4];
    #pragma unroll
    for (int nt = 0; nt < 4; ++nt)
        cb[nt] = conv_b[(oh * 4 + nt) * 16 + (lane & 15)];

    __syncthreads();

    f32x4 acc[4][4];
    #pragma unroll
    for (int mt = 0; mt < 4; ++mt)
        #pragma unroll
        for (int nt = 0; nt < 4; ++nt) {
            acc[mt][nt].x = cb[nt]; acc[mt][nt].y = cb[nt];
            acc[mt][nt].z = cb[nt]; acc[mt][nt].w = cb[nt];
        }

    #pragma unroll
    for (int mt = 0; mt < 4; ++mt) {
        const int w = (mh * 4 + mt) * 16 + (lane & 15);
        const int swz = (((w & 7) ^ ((w >> 3) & 7)) << 4);
        #pragma unroll
        for (int kk = 0; kk < 4; ++kk) {
            const int off = (w * 256 + kk * 64 + (lane >> 4) * 16) ^ swz;
            s16x8 Af = *(const s16x8*)((const char*)y_s + off);   // y^T fragment
            #pragma unroll
            for (int nt = 0; nt < 4; ++nt)
                acc[mt][nt] = __builtin_amdgcn_mfma_f32_16x16x32_bf16(
                    Af, Bf[nt][kk], acc[mt][nt], 0, 0, 0);
        }
    }

    __syncthreads();   // all y_s reads done; smem reusable as ystage

    // ---- epilogue: LDS-stage each o-half, then linear full-line stores ----
    const int w0s = (lane >> 4) * 4;
    #pragma unroll
    for (int p = 0; p < 2; ++p) {
        if (oh == p) {
            #pragma unroll
            for (int mt = 0; mt < 4; ++mt)
                #pragma unroll
                for (int nt = 0; nt < 4; ++nt) {
                    const int o_loc = nt * 16 + (lane & 15);
                    const int wrow  = (mh * 4 + mt) * 16 + w0s;
                    *(f32x4*)&ystage[o_loc * 132 + wrow] = acc[mt][nt];
                }
        }
        __syncthreads();
        #pragma unroll
        for (int i = 0; i < 8; ++i) {
            const int chunk = t + 256 * i;          // 0..2047
            const int o_loc = chunk >> 5;
            const int w4    = (chunk & 31) * 4;
            f32x4 v = *(const f32x4*)&ystage[o_loc * 132 + w4];
            const int o   = p * 64 + o_loc;
            const int idx = ((b * 128 + o) * 128 + h) * 128 + w4;
            f32x4 xr = *(const f32x4*)&x0[idx];
            const float a = att_ws[b * 128 + o];
            f32x4 rr;
            rr.x = v.x + xr.x * a; rr.y = v.y + xr.y * a;
            rr.z = v.z + xr.z * a; rr.w = v.w + xr.w * a;
            *(f32x4*)&out[idx] = rr;
        }
        __syncthreads();
    }
}

// ---------------------------------------------------------------------------
extern "C" void kernel_launch(void* const* d_in, const int* in_sizes, int n_in,
                              void* d_out, int out_size, void* d_ws, size_t ws_size,
                              hipStream_t stream) {
    const float* x0     = (const float*)d_in[0];
    const float* deg    = (const float*)d_in[1];
    const float* w1     = (const float*)d_in[2];
    const float* w2     = (const float*)d_in[3];
    const float* conv_w = (const float*)d_in[4];
    const float* conv_b = (const float*)d_in[5];
    const float* ca_w1  = (const float*)d_in[6];
    const float* ca_w2  = (const float*)d_in[7];
    float* out = (float*)d_out;

    // ws layout: kern 96KB | att 8KB | hid 8KB | Wp 32KB
    float* kern_ws = (float*)d_ws;
    float* att_ws  = kern_ws + 16 * 128 * 12;
    float* hid_ws  = att_ws + 16 * 128;
    uint16_t* Wp   = (uint16_t*)(hid_ws + 16 * 128);

    prep1_kernel<<<17, 128, 0, stream>>>(deg, w1, conv_w, ca_w1, ca_w2,
                                         hid_ws, att_ws, Wp);
    prep2_kernel<<<dim3(16, 6), 256, 0, stream>>>(hid_ws, w2, kern_ws);
    main_kernel<<<2048, 256, 0, stream>>>(x0, kern_ws, att_ws, Wp, conv_b, out);
}

// Round 3
// 358.273 us; speedup vs baseline: 1.6053x; 1.6053x over previous
//
#include <hip/hip_runtime.h>
#include <hip/hip_bf16.h>
#include <stdint.h>

typedef float  f32x4 __attribute__((ext_vector_type(4)));
typedef short  s16x8 __attribute__((ext_vector_type(8)));
typedef uint32_t u32x2 __attribute__((ext_vector_type(2)));

// round-to-nearest-even float -> bf16 bits (data has no NaN/Inf)
__device__ __forceinline__ uint16_t f2bf(float f) {
    union { float f; uint32_t u; } a; a.f = f;
    uint32_t r = a.u + 0x7FFFu + ((a.u >> 16) & 1u);
    return (uint16_t)(r >> 16);
}
__device__ __forceinline__ float lrelu(float v) { return fmaxf(v, 0.1f * v); }

// ---------------------------------------------------------------------------
// prep1: blocks 0..15 -> hidden (lrelu(deg@w1^T)) + CA attention for sample b.
//        block 16     -> pack conv_w into MFMA B-fragment order (bf16):
//        Wp[((ot*4+kk)*64+lane)*8+j] = conv_w[o=ot*16+(lane&15)][c=kk*32+(lane>>4)*8+j]
// ---------------------------------------------------------------------------
__global__ __launch_bounds__(128) void prep1_kernel(
    const float* __restrict__ deg, const float* __restrict__ w1,
    const float* __restrict__ conv_w, const float* __restrict__ ca_w1,
    const float* __restrict__ ca_w2,
    float* __restrict__ hid_ws, float* __restrict__ att_ws,
    uint16_t* __restrict__ Wp)
{
    const int t = threadIdx.x;
    if (blockIdx.x < 16) {
        const int b = blockIdx.x;
        __shared__ float sdeg[128];
        __shared__ float sh2[16];
        sdeg[t] = deg[b * 128 + t];
        __syncthreads();
        {
            float acc = 0.f;
            const float* w1r = w1 + t * 128;
            for (int c = 0; c < 128; ++c) acc += sdeg[c] * w1r[c];
            hid_ws[b * 128 + t] = lrelu(acc);
        }
        if (t < 16) {
            float a2 = 0.f;
            const float* cw = ca_w1 + t * 128;
            for (int c = 0; c < 128; ++c) a2 += sdeg[c] * cw[c];
            sh2[t] = lrelu(a2);
        }
        __syncthreads();
        {
            float aa = 0.f;
            const float* c2 = ca_w2 + t * 16;
            #pragma unroll
            for (int r = 0; r < 16; ++r) aa += sh2[r] * c2[r];
            att_ws[b * 128 + t] = 1.f / (1.f + expf(-aa));
        }
    } else {
        for (int idx = t; idx < 16384; idx += 128) {
            int j    = idx & 7;
            int lane = (idx >> 3) & 63;
            int kk   = (idx >> 9) & 3;
            int ot   = idx >> 11;
            int o = ot * 16 + (lane & 15);
            int c = kk * 32 + ((lane >> 4) & 3) * 8 + j;
            Wp[idx] = f2bf(conv_w[o * 128 + c]);
        }
    }
}

// ---------------------------------------------------------------------------
// prep2: kern taps. grid (16, 6) x 256 threads; thread -> one (c, tap) dot.
// ---------------------------------------------------------------------------
__global__ __launch_bounds__(256) void prep2_kernel(
    const float* __restrict__ hid_ws, const float* __restrict__ w2,
    float* __restrict__ kern_ws)
{
    const int b  = blockIdx.x;
    const int cj = blockIdx.y * 256 + threadIdx.x;   // 0..1535
    __shared__ f32x4 shid[32];
    if (threadIdx.x < 32)
        shid[threadIdx.x] = *(const f32x4*)(hid_ws + b * 128 + threadIdx.x * 4);
    __syncthreads();
    if (cj < 1152) {
        const int c = cj / 9, j = cj - c * 9;
        const f32x4* row = (const f32x4*)(w2 + cj * 128);
        float acc = 0.f;
        #pragma unroll 8
        for (int r = 0; r < 32; ++r) {
            f32x4 a = shid[r], v = row[r];
            acc += a.x * v.x + a.y * v.y + a.z * v.z + a.w * v.w;
        }
        kern_ws[(b * 128 + c) * 12 + j] = acc;
    } else {
        const int z = cj - 1152;
        const int c = z / 3, j = 9 + (z - (z / 3) * 3);
        kern_ws[(b * 128 + c) * 12 + j] = 0.f;
    }
}

// ---------------------------------------------------------------------------
// Main fused kernel: one block per (b, h) row; 512 threads = 8 waves.
//   Phase 1: depthwise 3x3 + lrelu -> bf16 y tile in LDS (w,c, XOR swizzle).
//            Thread: 4 channels x 8 w.
//   Phase 2: transposed MFMA GEMM D[w][o]; wave q -> w-half (q>>2) x
//            o-quarter (q&3): acc[4][2] (32 AGPR) + Bf[2][4] (32 VGPR).
//   Phase 3: two-pass LDS staging ([64][133] f32) -> fully-linear dwordx4
//            stores (full 128B lines) + residual x0*att.
// Register budget: ~90-110 total incl. AGPR, under the 128 cap from
// __launch_bounds__(512,4) (= 2 blocks/CU, 16 waves/CU). Round-2 lesson:
// VGPR_Count excludes AGPRs; cap is arch+acc combined.
// ---------------------------------------------------------------------------
__global__ __launch_bounds__(512, 4) void main_kernel(
    const float* __restrict__ x0, const float* __restrict__ kern_ws,
    const float* __restrict__ att_ws, const uint16_t* __restrict__ Wp,
    const float* __restrict__ conv_b, float* __restrict__ out)
{
    __shared__ char smem[64 * 133 * 4];            // 34048 B
    uint16_t* y_s    = (uint16_t*)smem;            // phase 1/2 view (32 KiB)
    float*    ystage = (float*)smem;               // phase 3 view [64][133]

    // XCD-aware swizzle (2048 % 8 == 0 -> bijective); adjacent h rows share halos.
    const int bid = blockIdx.x;
    const int lg  = (bid & 7) * 256 + (bid >> 3);
    const int b = lg >> 7;
    const int h = lg & 127;

    const int t    = threadIdx.x;
    const int lane = t & 63;
    const int q    = t >> 6;          // wave 0..7
    const int c0   = (t >> 4) * 4;    // channel quad (phase 1)
    const int w0   = (t & 15) * 8;    // w range (phase 1)

    // ---- kern taps for my 4 channels ----
    float kf[4][9];
    #pragma unroll
    for (int cc = 0; cc < 4; ++cc) {
        const float* kp = kern_ws + (b * 128 + c0 + cc) * 12;
        f32x4 ka = *(const f32x4*)kp;
        f32x4 kb = *(const f32x4*)(kp + 4);
        kf[cc][0] = ka.x; kf[cc][1] = ka.y; kf[cc][2] = ka.z; kf[cc][3] = ka.w;
        kf[cc][4] = kb.x; kf[cc][5] = kb.y; kf[cc][6] = kb.z; kf[cc][7] = kb.w;
        kf[cc][8] = kp[8];
    }

    // ---- depthwise 3x3 + lrelu -> packed bf16 ----
    uint32_t ypk[8][2];
    #pragma unroll
    for (int cc = 0; cc < 4; ++cc) {
        const int c = c0 + cc;
        const float* xpl = x0 + (b * 128 + c) * (128 * 128);
        float a8[8];
        #pragma unroll
        for (int i = 0; i < 8; ++i) a8[i] = 0.f;
        #pragma unroll
        for (int dr = 0; dr < 3; ++dr) {
            const int r = h - 1 + dr;
            f32x4 f0, f1;
            if ((unsigned)r < 128u) {
                const float* rp = xpl + r * 128 + w0;
                f0 = *(const f32x4*)rp;
                f1 = *(const f32x4*)(rp + 4);
            } else {
                f0.x = f0.y = f0.z = f0.w = 0.f;
                f1.x = f1.y = f1.z = f1.w = 0.f;
            }
            float lft = __shfl(f1.w, (lane - 1) & 63);
            float rgt = __shfl(f0.x, (lane + 1) & 63);
            if ((t & 15) == 0)  lft = 0.f;
            if ((t & 15) == 15) rgt = 0.f;
            const float k0 = kf[cc][dr * 3 + 0];
            const float k1 = kf[cc][dr * 3 + 1];
            const float k2 = kf[cc][dr * 3 + 2];
            a8[0] += k0 * lft  + k1 * f0.x + k2 * f0.y;
            a8[1] += k0 * f0.x + k1 * f0.y + k2 * f0.z;
            a8[2] += k0 * f0.y + k1 * f0.z + k2 * f0.w;
            a8[3] += k0 * f0.z + k1 * f0.w + k2 * f1.x;
            a8[4] += k0 * f0.w + k1 * f1.x + k2 * f1.y;
            a8[5] += k0 * f1.x + k1 * f1.y + k2 * f1.z;
            a8[6] += k0 * f1.y + k1 * f1.z + k2 * f1.w;
            a8[7] += k0 * f1.z + k1 * f1.w + k2 * rgt;
        }
        #pragma unroll
        for (int wi = 0; wi < 8; ++wi) {
            uint32_t u = f2bf(lrelu(a8[wi]));
            if ((cc & 1) == 0) ypk[wi][cc >> 1] = u;
            else               ypk[wi][cc >> 1] |= (u << 16);
        }
    }
    #pragma unroll
    for (int wi = 0; wi < 8; ++wi) {
        const int w = w0 + wi;
        int off = w * 256 + c0 * 2;
        off ^= (((w & 7) ^ ((w >> 3) & 7)) << 4);
        u32x2 v; v.x = ypk[wi][0]; v.y = ypk[wi][1];
        *(u32x2*)((char*)y_s + off) = v;
    }

    // ---- GEMM: wave q -> w-half mh, o-quarter oq; D[w][o] ----
    const int mh = q >> 2;
    const int oq = q & 3;
    s16x8 Bf[2][4];                              // W^T fragments (held in regs)
    #pragma unroll
    for (int nt = 0; nt < 2; ++nt)
        #pragma unroll
        for (int kk = 0; kk < 4; ++kk)
            Bf[nt][kk] = *(const s16x8*)(Wp + (((oq * 2 + nt) * 4 + kk) * 64 + lane) * 8);
    float cb[2];
    #pragma unroll
    for (int nt = 0; nt < 2; ++nt)
        cb[nt] = conv_b[(oq * 2 + nt) * 16 + (lane & 15)];

    __syncthreads();

    f32x4 acc[4][2];
    #pragma unroll
    for (int mt = 0; mt < 4; ++mt)
        #pragma unroll
        for (int nt = 0; nt < 2; ++nt) {
            acc[mt][nt].x = cb[nt]; acc[mt][nt].y = cb[nt];
            acc[mt][nt].z = cb[nt]; acc[mt][nt].w = cb[nt];
        }

    #pragma unroll
    for (int mt = 0; mt < 4; ++mt) {
        const int w = (mh * 4 + mt) * 16 + (lane & 15);
        const int swz = (((w & 7) ^ ((w >> 3) & 7)) << 4);
        #pragma unroll
        for (int kk = 0; kk < 4; ++kk) {
            const int off = (w * 256 + kk * 64 + (lane >> 4) * 16) ^ swz;
            s16x8 Af = *(const s16x8*)((const char*)y_s + off);  // y^T fragment
            #pragma unroll
            for (int nt = 0; nt < 2; ++nt)
                acc[mt][nt] = __builtin_amdgcn_mfma_f32_16x16x32_bf16(
                    Af, Bf[nt][kk], acc[mt][nt], 0, 0, 0);
        }
    }

    __syncthreads();   // all y_s reads done; smem reusable as ystage

    // ---- epilogue: stage each o-half in LDS, then linear full-line stores ----
    #pragma unroll
    for (int p = 0; p < 2; ++p) {
        if ((oq >> 1) == p) {
            #pragma unroll
            for (int mt = 0; mt < 4; ++mt)
                #pragma unroll
                for (int nt = 0; nt < 2; ++nt) {
                    const int o_loc = (oq & 1) * 32 + nt * 16 + (lane & 15);
                    const int wrow  = mh * 64 + mt * 16 + (lane >> 4) * 4;
                    *(f32x4*)&ystage[o_loc * 133 + wrow] = acc[mt][nt];
                }
        }
        __syncthreads();
        #pragma unroll
        for (int i = 0; i < 4; ++i) {
            const int chunk = t + 512 * i;          // 0..2047
            const int o_loc = chunk >> 5;           // 0..63
            const int w4    = (chunk & 31) * 4;
            f32x4 v = *(const f32x4*)&ystage[o_loc * 133 + w4];
            const int o   = p * 64 + o_loc;
            const int idx = ((b * 128 + o) * 128 + h) * 128 + w4;
            f32x4 xr = *(const f32x4*)&x0[idx];
            const float a = att_ws[b * 128 + o];
            f32x4 rr;
            rr.x = v.x + xr.x * a; rr.y = v.y + xr.y * a;
            rr.z = v.z + xr.z * a; rr.w = v.w + xr.w * a;
            *(f32x4*)&out[idx] = rr;
        }
        __syncthreads();
    }
}

// ---------------------------------------------------------------------------
extern "C" void kernel_launch(void* const* d_in, const int* in_sizes, int n_in,
                              void* d_out, int out_size, void* d_ws, size_t ws_size,
                              hipStream_t stream) {
    const float* x0     = (const float*)d_in[0];
    const float* deg    = (const float*)d_in[1];
    const float* w1     = (const float*)d_in[2];
    const float* w2     = (const float*)d_in[3];
    const float* conv_w = (const float*)d_in[4];
    const float* conv_b = (const float*)d_in[5];
    const float* ca_w1  = (const float*)d_in[6];
    const float* ca_w2  = (const float*)d_in[7];
    float* out = (float*)d_out;

    // ws layout: kern 96KB | att 8KB | hid 8KB | Wp 32KB
    float* kern_ws = (float*)d_ws;
    float* att_ws  = kern_ws + 16 * 128 * 12;
    float* hid_ws  = att_ws + 16 * 128;
    uint16_t* Wp   = (uint16_t*)(hid_ws + 16 * 128);

    prep1_kernel<<<17, 128, 0, stream>>>(deg, w1, conv_w, ca_w1, ca_w2,
                                         hid_ws, att_ws, Wp);
    prep2_kernel<<<dim3(16, 6), 256, 0, stream>>>(hid_ws, w2, kern_ws);
    main_kernel<<<2048, 512, 0, stream>>>(x0, kern_ws, att_ws, Wp, conv_b, out);
}